// Round 7
// baseline (204.410 us; speedup 1.0000x reference)
//
#include <hip/hip_runtime.h>
#include <hip/hip_bf16.h>
#include <stdint.h>

// Re-associated pipeline, all-f16 intermediates:
//   prep : qT=f16(q^T) + qH=f16(q) (one q read) | kH=f16(k)   [streaming]
//   gemm1: qk = qH @ kH^T  (f16 MFMA, 256^2 8-phase)          [qk f16, raw]
//   rowstats: per-row {m, 1/l} of softmax(0.125*qk)           [64 KB out]
//   gemm2a: tmp = softmax(qk) @ qT^T — normalization applied in-flight
//           during reg-staged A (raw qk -> exp -> f16 -> ds_write), f16 out
//   gemm2b: out = tmp @ kH^T   (f16, 256^2 8-phase, f32 out)
// Round 8: defer-normalization fusion. attn matrix never hits HBM (-33.5MB);
// prep reads q once (-33.5MB). All transforms bit-identical -> absmax 0.5.

#define SS 2048
#define DD 512
#define BATCH 4
#define NTB 8    // K tiles of 64 for K=512 (gemm1, gemm2b)
#define NT2A 32  // K tiles of 64 for K=2048 (gemm2a)

typedef __attribute__((ext_vector_type(8))) short short8;
typedef __attribute__((ext_vector_type(8))) _Float16 half8;
typedef __attribute__((ext_vector_type(4))) float floatx4;
typedef __attribute__((ext_vector_type(4))) float float4v;
typedef __attribute__((ext_vector_type(4))) unsigned int uintx4;

#define GLOBAL_AS const __attribute__((address_space(1)))
#define LDS_AS __attribute__((address_space(3)))

__device__ __forceinline__ uint32_t pk2h(float x, float y) {
    _Float16 hx = (_Float16)x, hy = (_Float16)y;   // RNE v_cvt_f16_f32
    union { _Float16 h; uint16_t u; } cx, cy;
    cx.h = hx; cy.h = hy;
    return (uint32_t)cx.u | ((uint32_t)cy.u << 16);
}
__device__ __forceinline__ float h2f(uint32_t ubits) {
    union { uint16_t u; _Float16 h; } c; c.u = (uint16_t)ubits; return (float)c.h;
}
__device__ __forceinline__ uint16_t f2h(float f) {
    union { _Float16 h; uint16_t u; } c; c.h = (_Float16)f; return c.u;
}

union PackU { uint32_t u[4]; short8 s8; };

// ---------------------------------------------------------------- prep
// y<8 : qT[b][d][u] = f16(q[b][u][d])  AND qH[b][u][d] = f16(q[b][u][d])
//       (transpose tiles; qH emitted from the same loaded data — q read once)
// y==8: kH[b][t][d] = f16(k[b][t][d])
__global__ __launch_bounds__(256) void prep_kernel(
    const float* __restrict__ Q, const float* __restrict__ K,
    uint16_t* __restrict__ qT, uint16_t* __restrict__ qH,
    uint16_t* __restrict__ kH)
{
    const int b   = blockIdx.z;
    const int tid = threadIdx.x;

    if (blockIdx.y == 8) {
        const float* src = K + (size_t)b * SS * DD;
        uint16_t* dst = kH + (size_t)b * SS * DD;
        const int g0 = blockIdx.x * 256 + tid;
#pragma unroll
        for (int i = 0; i < 16; ++i) {
            const int g = g0 + i * 8192;
            const float4v* s4 = (const float4v*)(src + (size_t)g * 8);
            float4v x0 = s4[0], x1 = s4[1];
            PackU p;
            p.u[0] = pk2h(x0[0], x0[1]);
            p.u[1] = pk2h(x0[2], x0[3]);
            p.u[2] = pk2h(x1[0], x1[1]);
            p.u[3] = pk2h(x1[2], x1[3]);
            *(short8*)(dst + (size_t)g * 8) = p.s8;
        }
        return;
    }

    const int u0 = blockIdx.x * 64;
    const int d0 = blockIdx.y * 64;
    const float* qb = Q + (size_t)b * SS * DD;
    uint16_t* qTb = qT + (size_t)b * DD * SS;
    uint16_t* qHb = qH + (size_t)b * SS * DD;

    __shared__ uint16_t T[64 * 66];

    {
        const int r  = tid >> 2;
        const int c4 = (tid & 3) * 16;
        const float* src = qb + (size_t)(u0 + r) * DD + d0 + c4;
        float4v x0 = *(const float4v*)(src + 0);
        float4v x1 = *(const float4v*)(src + 4);
        float4v x2 = *(const float4v*)(src + 8);
        float4v x3 = *(const float4v*)(src + 12);
        uint32_t w0 = pk2h(x0[0], x0[1]), w1 = pk2h(x0[2], x0[3]);
        uint32_t w2 = pk2h(x1[0], x1[1]), w3 = pk2h(x1[2], x1[3]);
        uint32_t w4 = pk2h(x2[0], x2[1]), w5 = pk2h(x2[2], x2[3]);
        uint32_t w6 = pk2h(x3[0], x3[1]), w7 = pk2h(x3[2], x3[3]);
        uint32_t* tw = (uint32_t*)&T[r * 66 + c4];
        tw[0] = w0; tw[1] = w1; tw[2] = w2; tw[3] = w3;
        tw[4] = w4; tw[5] = w5; tw[6] = w6; tw[7] = w7;
        // qH row-major write from the same converted data (q read once)
        PackU p;
        p.u[0] = w0; p.u[1] = w1; p.u[2] = w2; p.u[3] = w3;
        *(short8*)(&qHb[(size_t)(u0 + r) * DD + d0 + c4]) = p.s8;
        p.u[0] = w4; p.u[1] = w5; p.u[2] = w6; p.u[3] = w7;
        *(short8*)(&qHb[(size_t)(u0 + r) * DD + d0 + c4 + 8]) = p.s8;
    }
    __syncthreads();
#pragma unroll
    for (int p = 0; p < 2; ++p) {
        const int dl  = (tid >> 3) + p * 32;
        const int ul8 = (tid & 7) * 8;
        uint16_t t8[8];
#pragma unroll
        for (int j = 0; j < 8; ++j) t8[j] = T[(ul8 + j) * 66 + dl];
        PackU o;
        o.u[0] = (uint32_t)t8[0] | ((uint32_t)t8[1] << 16);
        o.u[1] = (uint32_t)t8[2] | ((uint32_t)t8[3] << 16);
        o.u[2] = (uint32_t)t8[4] | ((uint32_t)t8[5] << 16);
        o.u[3] = (uint32_t)t8[6] | ((uint32_t)t8[7] << 16);
        *(short8*)(&qTb[(size_t)(d0 + dl) * SS + u0 + ul8]) = o.s8;
    }
}

// ---------------------------------------------------------------- GEMM1
// qk[s][t] = sum_d qH[s][d]*kH[t][d] — 256^2 8-phase f16, NTB=8, f16 out.
__global__ __launch_bounds__(512, 2) void gemm1_kernel(
    const uint16_t* __restrict__ qH, const uint16_t* __restrict__ kH,
    uint16_t* __restrict__ qk)
{
    const int b  = blockIdx.z;
    const int s0 = blockIdx.y * 256;
    const int t0 = blockIdx.x * 256;
    const uint16_t* ab = qH + (size_t)b * SS * DD;
    const uint16_t* bb = kH + (size_t)b * SS * DD;

    __shared__ uint16_t smem[65536];

    const int tid  = threadIdx.x;
    const int lane = tid & 63;
    const int wave = tid >> 6;
    const int wm   = wave >> 2;
    const int wn   = wave & 3;
    const int fm   = lane & 15;
    const int quad = lane >> 4;

    floatx4 acc[8][4];
#pragma unroll
    for (int i = 0; i < 8; ++i)
#pragma unroll
        for (int j = 0; j < 4; ++j)
            acc[i][j] = (floatx4)0.0f;

    const int sl0  = (quad ^ (fm & 7)) * 8;
    const int aoff = (wm * 128 + fm) * 64;
    const int boff = 32768 + (wn * 64 + fm) * 64;

    const int c0 = wave * 128 + lane;
    const int r0 = c0 >> 3;  const int l0 = ((c0 & 7) ^ (r0 & 7)) * 8;
    const int c1 = c0 + 64;
    const int r1 = c1 >> 3;  const int l1 = ((c1 & 7) ^ (r1 & 7)) * 8;
    const int ldsW = wave * 1024;

    auto STAGE_A = [&](int tt, int h) {
        uint16_t* base = &smem[(tt & 1) * 16384 + h * 8192 + ldsW];
        __builtin_amdgcn_global_load_lds(
            (GLOBAL_AS void*)(ab + (size_t)(s0 + h * 128 + r0) * DD + tt * 64 + l0),
            (LDS_AS void*)(base), 16, 0, 0);
        __builtin_amdgcn_global_load_lds(
            (GLOBAL_AS void*)(ab + (size_t)(s0 + h * 128 + r1) * DD + tt * 64 + l1),
            (LDS_AS void*)(base + 512), 16, 0, 0);
    };
    auto STAGE_B = [&](int tt, int h) {
        uint16_t* base = &smem[32768 + (tt & 1) * 16384 + h * 8192 + ldsW];
        __builtin_amdgcn_global_load_lds(
            (GLOBAL_AS void*)(bb + (size_t)(t0 + h * 128 + r0) * DD + tt * 64 + l0),
            (LDS_AS void*)(base), 16, 0, 0);
        __builtin_amdgcn_global_load_lds(
            (GLOBAL_AS void*)(bb + (size_t)(t0 + h * 128 + r1) * DD + tt * 64 + l1),
            (LDS_AS void*)(base + 512), 16, 0, 0);
    };

    STAGE_A(0, 0); STAGE_A(0, 1); STAGE_B(0, 0); STAGE_B(0, 1);
    STAGE_B(1, 0); STAGE_B(1, 1);
    asm volatile("s_waitcnt vmcnt(4)" ::: "memory");
    __builtin_amdgcn_s_barrier();

    half8 aF[4], aF2[4], bF[4][2];

    for (int t = 0; t < NTB; ++t) {
        const int abase = (t & 1) * 16384;
        const int bbase = (t & 1) * 16384;

#pragma unroll
        for (int nt = 0; nt < 4; ++nt) {
            bF[nt][0] = *(const half8*)&smem[bbase + boff + nt * 1024 + sl0];
            bF[nt][1] = *(const half8*)&smem[bbase + boff + nt * 1024 + (sl0 ^ 32)];
        }
#pragma unroll
        for (int m = 0; m < 4; ++m)
            aF[m] = *(const half8*)&smem[abase + aoff + m * 1024 + sl0];
        if (t + 1 < NTB) STAGE_A(t + 1, 0);
        __builtin_amdgcn_s_barrier();
        asm volatile("s_waitcnt lgkmcnt(0)" ::: "memory");
        __builtin_amdgcn_s_setprio(1);
#pragma unroll
        for (int m = 0; m < 4; ++m)
#pragma unroll
            for (int nt = 0; nt < 4; ++nt)
                acc[m][nt] = __builtin_amdgcn_mfma_f32_16x16x32_f16(aF[m], bF[nt][0], acc[m][nt], 0, 0, 0);
        __builtin_amdgcn_s_setprio(0);
        __builtin_amdgcn_s_barrier();

#pragma unroll
        for (int m = 0; m < 4; ++m)
            aF2[m] = *(const half8*)&smem[abase + aoff + (m + 4) * 1024 + sl0];
        if (t + 1 < NTB) STAGE_A(t + 1, 1);
        __builtin_amdgcn_s_barrier();
        asm volatile("s_waitcnt lgkmcnt(0)" ::: "memory");
        __builtin_amdgcn_s_setprio(1);
#pragma unroll
        for (int m = 0; m < 4; ++m)
#pragma unroll
            for (int nt = 0; nt < 4; ++nt)
                acc[m + 4][nt] = __builtin_amdgcn_mfma_f32_16x16x32_f16(aF2[m], bF[nt][0], acc[m + 4][nt], 0, 0, 0);
        __builtin_amdgcn_s_setprio(0);
        __builtin_amdgcn_s_barrier();

#pragma unroll
        for (int m = 0; m < 4; ++m)
            aF[m] = *(const half8*)&smem[abase + aoff + m * 1024 + (sl0 ^ 32)];
        if (t + 2 < NTB) STAGE_B(t + 2, 0);
        __builtin_amdgcn_s_barrier();
        asm volatile("s_waitcnt lgkmcnt(0)" ::: "memory");
        __builtin_amdgcn_s_setprio(1);
#pragma unroll
        for (int m = 0; m < 4; ++m)
#pragma unroll
            for (int nt = 0; nt < 4; ++nt)
                acc[m][nt] = __builtin_amdgcn_mfma_f32_16x16x32_f16(aF[m], bF[nt][1], acc[m][nt], 0, 0, 0);
        __builtin_amdgcn_s_setprio(0);
        __builtin_amdgcn_s_barrier();

#pragma unroll
        for (int m = 0; m < 4; ++m)
            aF2[m] = *(const half8*)&smem[abase + aoff + (m + 4) * 1024 + (sl0 ^ 32)];
        if (t + 2 < NTB) {
            STAGE_B(t + 2, 1);
            asm volatile("s_waitcnt vmcnt(4)" ::: "memory");
        } else {
            asm volatile("s_waitcnt vmcnt(0)" ::: "memory");
        }
        __builtin_amdgcn_s_barrier();
        asm volatile("s_waitcnt lgkmcnt(0)" ::: "memory");
        __builtin_amdgcn_s_setprio(1);
#pragma unroll
        for (int m = 0; m < 4; ++m)
#pragma unroll
            for (int nt = 0; nt < 4; ++nt)
                acc[m + 4][nt] = __builtin_amdgcn_mfma_f32_16x16x32_f16(aF2[m], bF[nt][1], acc[m + 4][nt], 0, 0, 0);
        __builtin_amdgcn_s_setprio(0);
        __builtin_amdgcn_s_barrier();
    }

    uint16_t* ob = qk + (size_t)b * SS * SS;
#pragma unroll
    for (int mt = 0; mt < 8; ++mt) {
#pragma unroll
        for (int nt = 0; nt < 4; ++nt) {
            const int srow = s0 + wm * 128 + mt * 16 + quad * 4;
            const int tcol = t0 + wn * 64 + nt * 16 + fm;
#pragma unroll
            for (int reg = 0; reg < 4; ++reg)
                ob[(size_t)(srow + reg) * SS + tcol] = f2h(acc[mt][nt][reg]);
        }
    }
}

// ---------------------------------------------------------------- rowstats
// per row of raw qk: m = max(0.125*x), l = sum exp(0.125*x - m);
// stats[row] = {m, 1/l}. Same reduction trees as the old softmax -> bits match.
__global__ __launch_bounds__(256) void rowstats_kernel(
    const uint16_t* __restrict__ qk, float2* __restrict__ stats)
{
    const size_t row = blockIdx.x;
    const uint16_t* x = qk + row * SS;
    const int tid  = threadIdx.x;
    const int lane = tid & 63;
    const int wave = tid >> 6;

    uintx4 raw = *(const uintx4*)(x + tid * 8);
    float v[8];
#pragma unroll
    for (int i = 0; i < 4; ++i) {
        uint32_t u = raw[i];
        v[2 * i]     = h2f(u & 0xffffu) * 0.125f;
        v[2 * i + 1] = h2f(u >> 16) * 0.125f;
    }
    float m = v[0];
#pragma unroll
    for (int j = 1; j < 8; ++j) m = fmaxf(m, v[j]);
#pragma unroll
    for (int off = 1; off < 64; off <<= 1) m = fmaxf(m, __shfl_xor(m, off, 64));
    __shared__ float red[8];
    if (lane == 0) red[wave] = m;
    __syncthreads();
    m = fmaxf(fmaxf(red[0], red[1]), fmaxf(red[2], red[3]));

    float s = 0.f;
#pragma unroll
    for (int j = 0; j < 8; ++j) s += __expf(v[j] - m);
#pragma unroll
    for (int off = 1; off < 64; off <<= 1) s += __shfl_xor(s, off, 64);
    if (lane == 0) red[4 + wave] = s;
    __syncthreads();
    s = (red[4] + red[5]) + (red[6] + red[7]);
    if (tid == 0) stats[row] = make_float2(m, 1.0f / s);
}

// ---------------------------------------------------------------- GEMM2a
// tmp[s][d] = sum_u attn[s][u] * qT[d][u], attn = softmax applied IN-FLIGHT:
// A staged via registers from raw qk (same inverse-swizzled addresses),
// converted f16(exp(v - m)*invl), ds_write_b128 to the slots gload_lds used.
// B (qT) stays gload_lds. 4 VMEM/iter: [A-reg x2 (P1)] [B-lds x2 (P2)];
// steady-state vmcnt(2) leaves only B(t+2) in flight -> A(t+2) regs + B(t+1)
// landed. 2 barriers/iter, distance-2 prefetch, never drains.
// attn math bit-identical to the old softmax kernel -> absmax must stay 0.5.
__global__ __launch_bounds__(512, 2) void gemm2a_kernel(
    const uint16_t* __restrict__ qk, const uint16_t* __restrict__ qT,
    const float2* __restrict__ stats, uint16_t* __restrict__ tmp)
{
    const int b  = blockIdx.z;
    const int s0 = blockIdx.y * 128;
    const int t0 = blockIdx.x * 128;   // d-dim tile, 0..511
    const uint16_t* ab = qk + (size_t)b * SS * SS;   // ld SS (raw scores)
    const uint16_t* bb = qT + (size_t)b * DD * SS;   // ld SS

    // halfs: Abuf0 [0,8192) Abuf1 [8192,16384) Bbuf0 [16384,24576) Bbuf1 [24576,32768)
    __shared__ uint16_t smem[32768];   // 64 KiB

    const int tid  = threadIdx.x;
    const int lane = tid & 63;
    const int wave = tid >> 6;
    const int wm   = wave >> 2;   // 0..1 (M half: 64 rows)
    const int wn   = wave & 3;    // 0..3 (N quarter: 32 cols)
    const int fm   = lane & 15;
    const int quad = lane >> 4;

    floatx4 acc[4][2];
#pragma unroll
    for (int i = 0; i < 4; ++i)
#pragma unroll
        for (int j = 0; j < 2; ++j)
            acc[i][j] = (floatx4)0.0f;

    const int sl0  = (quad ^ (fm & 7)) * 8;           // ks0 ; ks1 -> sl0^32
    const int aoff = (wm * 64 + fm) * 64;             // + mt*1024 + slot
    const int boff = 16384 + (wn * 32 + fm) * 64;     // + nt*1024 + slot

    // staging geometry (identical addresses to the old gload_lds A path)
    const int r0 = tid >> 3;                           // rows 0..63
    const int l0 = (((tid & 7) ^ (r0 & 7))) * 8;
    const int r1 = r0 + 64;                            // rows 64..127
    const int l1 = l0;                                 // r1&7 == r0&7
    const int ldsW = wave * 512;                       // + lane*8 per chunk

    // per-row softmax stats (rows fixed per thread for the whole kernel)
    const float2 st0 = stats[(size_t)b * SS + s0 + r0];
    const float2 st1 = stats[(size_t)b * SS + s0 + r1];

    auto LOAD_A = [&](int tt, uintx4& ua, uintx4& ub) {
        ua = *(const uintx4*)(ab + (size_t)(s0 + r0) * SS + tt * 64 + l0);
        ub = *(const uintx4*)(ab + (size_t)(s0 + r1) * SS + tt * 64 + l1);
    };
    auto WRITE_A = [&](int tt, const uintx4& ua, const uintx4& ub) {
        uint16_t* base = &smem[(tt & 1) * 8192 + ldsW + lane * 8];
        PackU p;
#pragma unroll
        for (int j = 0; j < 4; ++j) {
            uint32_t u = ua[j];
            float va = h2f(u & 0xffffu) * 0.125f;
            float vb = h2f(u >> 16) * 0.125f;
            p.u[j] = pk2h(__expf(va - st0.x) * st0.y, __expf(vb - st0.x) * st0.y);
        }
        *(short8*)base = p.s8;
#pragma unroll
        for (int j = 0; j < 4; ++j) {
            uint32_t u = ub[j];
            float va = h2f(u & 0xffffu) * 0.125f;
            float vb = h2f(u >> 16) * 0.125f;
            p.u[j] = pk2h(__expf(va - st1.x) * st1.y, __expf(vb - st1.x) * st1.y);
        }
        *(short8*)(base + 4096) = p.s8;
    };
    auto STAGE_B = [&](int tt) {
        uint16_t* base = &smem[16384 + (tt & 1) * 8192 + ldsW];
        __builtin_amdgcn_global_load_lds(
            (GLOBAL_AS void*)(bb + (size_t)(t0 + r0) * SS + tt * 64 + l0),
            (LDS_AS void*)(base), 16, 0, 0);
        __builtin_amdgcn_global_load_lds(
            (GLOBAL_AS void*)(bb + (size_t)(t0 + r1) * SS + tt * 64 + l1),
            (LDS_AS void*)(base + 4096), 16, 0, 0);
    };

    // prologue: A0,A1 to regs; B0,B1 gload_lds. Issue order pinned by fence.
    uintx4 a0a, a0b, a1a, a1b;
    LOAD_A(0, a0a, a0b);
    LOAD_A(1, a1a, a1b);
    asm volatile("" ::: "memory");   // pin: A loads issue before B loads
    STAGE_B(0); STAGE_B(1);
    asm volatile("s_waitcnt vmcnt(2)" ::: "memory");   // A0,A1,B0 done; B1 in flight
    WRITE_A(0, a0a, a0b);
    WRITE_A(1, a1a, a1b);
    asm volatile("s_waitcnt lgkmcnt(0)" ::: "memory");
    __builtin_amdgcn_s_barrier();

    half8 aF[4][2], bF[2][2];

    for (int t = 0; t < NT2A; ++t) {
        const int buf = (t & 1) * 8192;

        // ===== P1: ds_read all 12 frags of tile t ; issue A-regs(t+2) ; MFMA ks0
        uintx4 nA0, nA1;
#pragma unroll
        for (int m = 0; m < 4; ++m) {
            aF[m][0] = *(const half8*)&smem[buf + aoff + m * 1024 + sl0];
            aF[m][1] = *(const half8*)&smem[buf + aoff + m * 1024 + (sl0 ^ 32)];
        }
#pragma unroll
        for (int n = 0; n < 2; ++n) {
            bF[n][0] = *(const half8*)&smem[buf + boff + n * 1024 + sl0];
            bF[n][1] = *(const half8*)&smem[buf + boff + n * 1024 + (sl0 ^ 32)];
        }
        if (t + 2 < NT2A) LOAD_A(t + 2, nA0, nA1);
        asm volatile("s_waitcnt lgkmcnt(0)" ::: "memory");
        __builtin_amdgcn_s_setprio(1);
#pragma unroll
        for (int m = 0; m < 4; ++m)
#pragma unroll
            for (int n = 0; n < 2; ++n)
                acc[m][n] = __builtin_amdgcn_mfma_f32_16x16x32_f16(aF[m][0], bF[n][0], acc[m][n], 0, 0, 0);
        __builtin_amdgcn_s_setprio(0);
        __builtin_amdgcn_s_barrier();   // bar1: all waves done reading tile t

        // ===== P2: B-lds(t+2) ; vmcnt(2) ; convert+write A(t+2) ; bar2 ; MFMA ks1
        if (t + 2 < NT2A) {
            STAGE_B(t + 2);
            asm volatile("s_waitcnt vmcnt(2)" ::: "memory");   // A(t+2) regs + B(t+1) landed
            WRITE_A(t + 2, nA0, nA1);
            asm volatile("s_waitcnt lgkmcnt(0)" ::: "memory"); // ds_writes committed
        } else {
            asm volatile("s_waitcnt vmcnt(0)" ::: "memory");
        }
        __builtin_amdgcn_s_barrier();   // bar2: tile t+1 resident for every wave
        __builtin_amdgcn_s_setprio(1);
#pragma unroll
        for (int m = 0; m < 4; ++m)
#pragma unroll
            for (int n = 0; n < 2; ++n)
                acc[m][n] = __builtin_amdgcn_mfma_f32_16x16x32_f16(aF[m][1], bF[n][1], acc[m][n], 0, 0, 0);
        __builtin_amdgcn_s_setprio(0);
    }

    uint16_t* tb = tmp + (size_t)b * SS * DD;
#pragma unroll
    for (int mt = 0; mt < 4; ++mt) {
#pragma unroll
        for (int n = 0; n < 2; ++n) {
            const int srw  = s0 + wm * 64 + mt * 16 + quad * 4;
            const int tcol = t0 + wn * 32 + n * 16 + fm;
#pragma unroll
            for (int reg = 0; reg < 4; ++reg)
                tb[(size_t)(srw + reg) * DD + tcol] = f2h(acc[mt][n][reg]);
        }
    }
}

// ---------------------------------------------------------------- GEMM2b
// out[s][t] = sum_d tmp[s][d] * kH[t][d]  (f16, 256^2 8-phase, f32 out)
__global__ __launch_bounds__(512, 2) void gemm2b_kernel(
    const uint16_t* __restrict__ tmp, const uint16_t* __restrict__ kH,
    float* __restrict__ out)
{
    const int b  = blockIdx.z;
    const int s0 = blockIdx.y * 256;
    const int t0 = blockIdx.x * 256;
    const uint16_t* ab = tmp + (size_t)b * SS * DD;
    const uint16_t* bb = kH  + (size_t)b * SS * DD;

    __shared__ uint16_t smem[65536];

    const int tid  = threadIdx.x;
    const int lane = tid & 63;
    const int wave = tid >> 6;
    const int wm   = wave >> 2;
    const int wn   = wave & 3;
    const int fm   = lane & 15;
    const int quad = lane >> 4;

    floatx4 acc[8][4];
#pragma unroll
    for (int i = 0; i < 8; ++i)
#pragma unroll
        for (int j = 0; j < 4; ++j)
            acc[i][j] = (floatx4)0.0f;

    const int sl0  = (quad ^ (fm & 7)) * 8;
    const int aoff = (wm * 128 + fm) * 64;
    const int boff = 32768 + (wn * 64 + fm) * 64;

    const int c0 = wave * 128 + lane;
    const int r0 = c0 >> 3;  const int l0 = ((c0 & 7) ^ (r0 & 7)) * 8;
    const int c1 = c0 + 64;
    const int r1 = c1 >> 3;  const int l1 = ((c1 & 7) ^ (r1 & 7)) * 8;
    const int ldsW = wave * 1024;

    auto STAGE_A = [&](int tt, int h) {
        uint16_t* base = &smem[(tt & 1) * 16384 + h * 8192 + ldsW];
        __builtin_amdgcn_global_load_lds(
            (GLOBAL_AS void*)(ab + (size_t)(s0 + h * 128 + r0) * DD + tt * 64 + l0),
            (LDS_AS void*)(base), 16, 0, 0);
        __builtin_amdgcn_global_load_lds(
            (GLOBAL_AS void*)(ab + (size_t)(s0 + h * 128 + r1) * DD + tt * 64 + l1),
            (LDS_AS void*)(base + 512), 16, 0, 0);
    };
    auto STAGE_B = [&](int tt, int h) {
        uint16_t* base = &smem[32768 + (tt & 1) * 16384 + h * 8192 + ldsW];
        __builtin_amdgcn_global_load_lds(
            (GLOBAL_AS void*)(bb + (size_t)(t0 + h * 128 + r0) * DD + tt * 64 + l0),
            (LDS_AS void*)(base), 16, 0, 0);
        __builtin_amdgcn_global_load_lds(
            (GLOBAL_AS void*)(bb + (size_t)(t0 + h * 128 + r1) * DD + tt * 64 + l1),
            (LDS_AS void*)(base + 512), 16, 0, 0);
    };

    STAGE_A(0, 0); STAGE_A(0, 1); STAGE_B(0, 0); STAGE_B(0, 1);
    STAGE_B(1, 0); STAGE_B(1, 1);
    asm volatile("s_waitcnt vmcnt(4)" ::: "memory");
    __builtin_amdgcn_s_barrier();

    half8 aF[4], aF2[4], bF[4][2];

    for (int t = 0; t < NTB; ++t) {
        const int abase = (t & 1) * 16384;
        const int bbase = (t & 1) * 16384;

#pragma unroll
        for (int nt = 0; nt < 4; ++nt) {
            bF[nt][0] = *(const half8*)&smem[bbase + boff + nt * 1024 + sl0];
            bF[nt][1] = *(const half8*)&smem[bbase + boff + nt * 1024 + (sl0 ^ 32)];
        }
#pragma unroll
        for (int m = 0; m < 4; ++m)
            aF[m] = *(const half8*)&smem[abase + aoff + m * 1024 + sl0];
        if (t + 1 < NTB) STAGE_A(t + 1, 0);
        __builtin_amdgcn_s_barrier();
        asm volatile("s_waitcnt lgkmcnt(0)" ::: "memory");
        __builtin_amdgcn_s_setprio(1);
#pragma unroll
        for (int m = 0; m < 4; ++m)
#pragma unroll
            for (int nt = 0; nt < 4; ++nt)
                acc[m][nt] = __builtin_amdgcn_mfma_f32_16x16x32_f16(aF[m], bF[nt][0], acc[m][nt], 0, 0, 0);
        __builtin_amdgcn_s_setprio(0);
        __builtin_amdgcn_s_barrier();

#pragma unroll
        for (int m = 0; m < 4; ++m)
            aF2[m] = *(const half8*)&smem[abase + aoff + (m + 4) * 1024 + sl0];
        if (t + 1 < NTB) STAGE_A(t + 1, 1);
        __builtin_amdgcn_s_barrier();
        asm volatile("s_waitcnt lgkmcnt(0)" ::: "memory");
        __builtin_amdgcn_s_setprio(1);
#pragma unroll
        for (int m = 0; m < 4; ++m)
#pragma unroll
            for (int nt = 0; nt < 4; ++nt)
                acc[m + 4][nt] = __builtin_amdgcn_mfma_f32_16x16x32_f16(aF2[m], bF[nt][0], acc[m + 4][nt], 0, 0, 0);
        __builtin_amdgcn_s_setprio(0);
        __builtin_amdgcn_s_barrier();

#pragma unroll
        for (int m = 0; m < 4; ++m)
            aF[m] = *(const half8*)&smem[abase + aoff + m * 1024 + (sl0 ^ 32)];
        if (t + 2 < NTB) STAGE_B(t + 2, 0);
        __builtin_amdgcn_s_barrier();
        asm volatile("s_waitcnt lgkmcnt(0)" ::: "memory");
        __builtin_amdgcn_s_setprio(1);
#pragma unroll
        for (int m = 0; m < 4; ++m)
#pragma unroll
            for (int nt = 0; nt < 4; ++nt)
                acc[m][nt] = __builtin_amdgcn_mfma_f32_16x16x32_f16(aF[m], bF[nt][1], acc[m][nt], 0, 0, 0);
        __builtin_amdgcn_s_setprio(0);
        __builtin_amdgcn_s_barrier();

#pragma unroll
        for (int m = 0; m < 4; ++m)
            aF2[m] = *(const half8*)&smem[abase + aoff + (m + 4) * 1024 + (sl0 ^ 32)];
        if (t + 2 < NTB) {
            STAGE_B(t + 2, 1);
            asm volatile("s_waitcnt vmcnt(4)" ::: "memory");
        } else {
            asm volatile("s_waitcnt vmcnt(0)" ::: "memory");
        }
        __builtin_amdgcn_s_barrier();
        asm volatile("s_waitcnt lgkmcnt(0)" ::: "memory");
        __builtin_amdgcn_s_setprio(1);
#pragma unroll
        for (int m = 0; m < 4; ++m)
#pragma unroll
            for (int nt = 0; nt < 4; ++nt)
                acc[m + 4][nt] = __builtin_amdgcn_mfma_f32_16x16x32_f16(aF2[m], bF[nt][1], acc[m + 4][nt], 0, 0, 0);
        __builtin_amdgcn_s_setprio(0);
        __builtin_amdgcn_s_barrier();
    }

    float* ob = out + (size_t)b * SS * SS;
#pragma unroll
    for (int mt = 0; mt < 8; ++mt) {
#pragma unroll
        for (int nt = 0; nt < 4; ++nt) {
            const int srow = s0 + wm * 128 + mt * 16 + quad * 4;
            const int tcol = t0 + wn * 64 + nt * 16 + fm;
#pragma unroll
            for (int reg = 0; reg < 4; ++reg)
                ob[(size_t)(srow + reg) * SS + tcol] = acc[mt][nt][reg];
        }
    }
}

extern "C" void kernel_launch(void* const* d_in, const int* in_sizes, int n_in,
                              void* d_out, int out_size, void* d_ws, size_t ws_size,
                              hipStream_t stream) {
    const float* q = (const float*)d_in[0];
    const float* k = (const float*)d_in[1];
    float* out = (float*)d_out;

    uint16_t* qk  = (uint16_t*)d_ws;                   // 4*2048*2048
    uint16_t* qT  = qk + (size_t)BATCH * SS * SS;      // 4*512*2048
    uint16_t* qH  = qT + (size_t)BATCH * DD * SS;      // 4*2048*512
    uint16_t* kH  = qH + (size_t)BATCH * SS * DD;      // 4*2048*512
    uint16_t* tmp = kH + (size_t)BATCH * SS * DD;      // 4*2048*512
    float2* stats = (float2*)(tmp + (size_t)BATCH * SS * DD);  // 4*2048 pairs

    prep_kernel<<<dim3(32, 9, BATCH), 256, 0, stream>>>(q, k, qT, qH, kH);
    gemm1_kernel<<<dim3(SS / 256, SS / 256, BATCH), 512, 0, stream>>>(qH, kH, qk);
    rowstats_kernel<<<dim3(BATCH * SS), 256, 0, stream>>>(qk, stats);
    gemm2a_kernel<<<dim3(DD / 128, SS / 128, BATCH), 512, 0, stream>>>(qk, qT, stats, tmp);
    gemm2b_kernel<<<dim3(SS / 256, SS / 256, BATCH), 512, 0, stream>>>(tmp, kH, out);
}

// Round 8
// 199.012 us; speedup vs baseline: 1.0271x; 1.0271x over previous
//
#include <hip/hip_runtime.h>
#include <hip/hip_bf16.h>
#include <stdint.h>

// Re-associated pipeline, all-f16 intermediates:
//   prep : qT=f16(q^T) + qH=f16(q) (one q read) | kH=f16(k)   [streaming]
//   gemm1: qk = qH @ kH^T  (f16 MFMA, 256^2 8-phase)          [qk f16, raw]
//   rowstats: per-row {m, 1/l} of softmax(0.125*qk)           [64 KB out]
//   gemm2a: tmp = softmax(qk) @ qT^T — fused normalization, exp moved to P1
//           (overlaps ds_read latency; 3-deep A-buffer rotation), f16 out
//   gemm2b: out = tmp @ kH^T   (f16, 256^2 8-phase, f32 out)
// Round 9: fix R7 regression — exp chain was serialized between vmcnt and
// barrier in P2 (VALUBusy 26%, MfmaUtil 12%). Now WRITE_A(t+2) runs in P1
// under the in-flight ds_reads; A rotates through 3 LDS buffers so the write
// never collides with readers (2-barrier separation). Math bit-identical
// to R7 (verified) -> absmax must stay 0.5.

#define SS 2048
#define DD 512
#define BATCH 4
#define NTB 8    // K tiles of 64 for K=512 (gemm1, gemm2b)
#define NT2A 32  // K tiles of 64 for K=2048 (gemm2a)

typedef __attribute__((ext_vector_type(8))) short short8;
typedef __attribute__((ext_vector_type(8))) _Float16 half8;
typedef __attribute__((ext_vector_type(4))) float floatx4;
typedef __attribute__((ext_vector_type(4))) float float4v;
typedef __attribute__((ext_vector_type(4))) unsigned int uintx4;

#define GLOBAL_AS const __attribute__((address_space(1)))
#define LDS_AS __attribute__((address_space(3)))

__device__ __forceinline__ uint32_t pk2h(float x, float y) {
    _Float16 hx = (_Float16)x, hy = (_Float16)y;   // RNE v_cvt_f16_f32
    union { _Float16 h; uint16_t u; } cx, cy;
    cx.h = hx; cy.h = hy;
    return (uint32_t)cx.u | ((uint32_t)cy.u << 16);
}
__device__ __forceinline__ float h2f(uint32_t ubits) {
    union { uint16_t u; _Float16 h; } c; c.u = (uint16_t)ubits; return (float)c.h;
}
__device__ __forceinline__ uint16_t f2h(float f) {
    union { _Float16 h; uint16_t u; } c; c.h = (_Float16)f; return c.u;
}

union PackU { uint32_t u[4]; short8 s8; };

// ---------------------------------------------------------------- prep
// y<8 : qT[b][d][u] = f16(q[b][u][d])  AND qH[b][u][d] (q read once)
// y==8: kH[b][t][d] = f16(k[b][t][d])
__global__ __launch_bounds__(256) void prep_kernel(
    const float* __restrict__ Q, const float* __restrict__ K,
    uint16_t* __restrict__ qT, uint16_t* __restrict__ qH,
    uint16_t* __restrict__ kH)
{
    const int b   = blockIdx.z;
    const int tid = threadIdx.x;

    if (blockIdx.y == 8) {
        const float* src = K + (size_t)b * SS * DD;
        uint16_t* dst = kH + (size_t)b * SS * DD;
        const int g0 = blockIdx.x * 256 + tid;
#pragma unroll
        for (int i = 0; i < 16; ++i) {
            const int g = g0 + i * 8192;
            const float4v* s4 = (const float4v*)(src + (size_t)g * 8);
            float4v x0 = s4[0], x1 = s4[1];
            PackU p;
            p.u[0] = pk2h(x0[0], x0[1]);
            p.u[1] = pk2h(x0[2], x0[3]);
            p.u[2] = pk2h(x1[0], x1[1]);
            p.u[3] = pk2h(x1[2], x1[3]);
            *(short8*)(dst + (size_t)g * 8) = p.s8;
        }
        return;
    }

    const int u0 = blockIdx.x * 64;
    const int d0 = blockIdx.y * 64;
    const float* qb = Q + (size_t)b * SS * DD;
    uint16_t* qTb = qT + (size_t)b * DD * SS;
    uint16_t* qHb = qH + (size_t)b * SS * DD;

    __shared__ uint16_t T[64 * 66];

    {
        const int r  = tid >> 2;
        const int c4 = (tid & 3) * 16;
        const float* src = qb + (size_t)(u0 + r) * DD + d0 + c4;
        float4v x0 = *(const float4v*)(src + 0);
        float4v x1 = *(const float4v*)(src + 4);
        float4v x2 = *(const float4v*)(src + 8);
        float4v x3 = *(const float4v*)(src + 12);
        uint32_t w0 = pk2h(x0[0], x0[1]), w1 = pk2h(x0[2], x0[3]);
        uint32_t w2 = pk2h(x1[0], x1[1]), w3 = pk2h(x1[2], x1[3]);
        uint32_t w4 = pk2h(x2[0], x2[1]), w5 = pk2h(x2[2], x2[3]);
        uint32_t w6 = pk2h(x3[0], x3[1]), w7 = pk2h(x3[2], x3[3]);
        uint32_t* tw = (uint32_t*)&T[r * 66 + c4];
        tw[0] = w0; tw[1] = w1; tw[2] = w2; tw[3] = w3;
        tw[4] = w4; tw[5] = w5; tw[6] = w6; tw[7] = w7;
        PackU p;
        p.u[0] = w0; p.u[1] = w1; p.u[2] = w2; p.u[3] = w3;
        *(short8*)(&qHb[(size_t)(u0 + r) * DD + d0 + c4]) = p.s8;
        p.u[0] = w4; p.u[1] = w5; p.u[2] = w6; p.u[3] = w7;
        *(short8*)(&qHb[(size_t)(u0 + r) * DD + d0 + c4 + 8]) = p.s8;
    }
    __syncthreads();
#pragma unroll
    for (int p = 0; p < 2; ++p) {
        const int dl  = (tid >> 3) + p * 32;
        const int ul8 = (tid & 7) * 8;
        uint16_t t8[8];
#pragma unroll
        for (int j = 0; j < 8; ++j) t8[j] = T[(ul8 + j) * 66 + dl];
        PackU o;
        o.u[0] = (uint32_t)t8[0] | ((uint32_t)t8[1] << 16);
        o.u[1] = (uint32_t)t8[2] | ((uint32_t)t8[3] << 16);
        o.u[2] = (uint32_t)t8[4] | ((uint32_t)t8[5] << 16);
        o.u[3] = (uint32_t)t8[6] | ((uint32_t)t8[7] << 16);
        *(short8*)(&qTb[(size_t)(d0 + dl) * SS + u0 + ul8]) = o.s8;
    }
}

// ---------------------------------------------------------------- GEMM1
// qk[s][t] = sum_d qH[s][d]*kH[t][d] — 256^2 8-phase f16, NTB=8, f16 out.
__global__ __launch_bounds__(512, 2) void gemm1_kernel(
    const uint16_t* __restrict__ qH, const uint16_t* __restrict__ kH,
    uint16_t* __restrict__ qk)
{
    const int b  = blockIdx.z;
    const int s0 = blockIdx.y * 256;
    const int t0 = blockIdx.x * 256;
    const uint16_t* ab = qH + (size_t)b * SS * DD;
    const uint16_t* bb = kH + (size_t)b * SS * DD;

    __shared__ uint16_t smem[65536];

    const int tid  = threadIdx.x;
    const int lane = tid & 63;
    const int wave = tid >> 6;
    const int wm   = wave >> 2;
    const int wn   = wave & 3;
    const int fm   = lane & 15;
    const int quad = lane >> 4;

    floatx4 acc[8][4];
#pragma unroll
    for (int i = 0; i < 8; ++i)
#pragma unroll
        for (int j = 0; j < 4; ++j)
            acc[i][j] = (floatx4)0.0f;

    const int sl0  = (quad ^ (fm & 7)) * 8;
    const int aoff = (wm * 128 + fm) * 64;
    const int boff = 32768 + (wn * 64 + fm) * 64;

    const int c0 = wave * 128 + lane;
    const int r0 = c0 >> 3;  const int l0 = ((c0 & 7) ^ (r0 & 7)) * 8;
    const int c1 = c0 + 64;
    const int r1 = c1 >> 3;  const int l1 = ((c1 & 7) ^ (r1 & 7)) * 8;
    const int ldsW = wave * 1024;

    auto STAGE_A = [&](int tt, int h) {
        uint16_t* base = &smem[(tt & 1) * 16384 + h * 8192 + ldsW];
        __builtin_amdgcn_global_load_lds(
            (GLOBAL_AS void*)(ab + (size_t)(s0 + h * 128 + r0) * DD + tt * 64 + l0),
            (LDS_AS void*)(base), 16, 0, 0);
        __builtin_amdgcn_global_load_lds(
            (GLOBAL_AS void*)(ab + (size_t)(s0 + h * 128 + r1) * DD + tt * 64 + l1),
            (LDS_AS void*)(base + 512), 16, 0, 0);
    };
    auto STAGE_B = [&](int tt, int h) {
        uint16_t* base = &smem[32768 + (tt & 1) * 16384 + h * 8192 + ldsW];
        __builtin_amdgcn_global_load_lds(
            (GLOBAL_AS void*)(bb + (size_t)(t0 + h * 128 + r0) * DD + tt * 64 + l0),
            (LDS_AS void*)(base), 16, 0, 0);
        __builtin_amdgcn_global_load_lds(
            (GLOBAL_AS void*)(bb + (size_t)(t0 + h * 128 + r1) * DD + tt * 64 + l1),
            (LDS_AS void*)(base + 512), 16, 0, 0);
    };

    STAGE_A(0, 0); STAGE_A(0, 1); STAGE_B(0, 0); STAGE_B(0, 1);
    STAGE_B(1, 0); STAGE_B(1, 1);
    asm volatile("s_waitcnt vmcnt(4)" ::: "memory");
    __builtin_amdgcn_s_barrier();

    half8 aF[4], aF2[4], bF[4][2];

    for (int t = 0; t < NTB; ++t) {
        const int abase = (t & 1) * 16384;
        const int bbase = (t & 1) * 16384;

#pragma unroll
        for (int nt = 0; nt < 4; ++nt) {
            bF[nt][0] = *(const half8*)&smem[bbase + boff + nt * 1024 + sl0];
            bF[nt][1] = *(const half8*)&smem[bbase + boff + nt * 1024 + (sl0 ^ 32)];
        }
#pragma unroll
        for (int m = 0; m < 4; ++m)
            aF[m] = *(const half8*)&smem[abase + aoff + m * 1024 + sl0];
        if (t + 1 < NTB) STAGE_A(t + 1, 0);
        __builtin_amdgcn_s_barrier();
        asm volatile("s_waitcnt lgkmcnt(0)" ::: "memory");
        __builtin_amdgcn_s_setprio(1);
#pragma unroll
        for (int m = 0; m < 4; ++m)
#pragma unroll
            for (int nt = 0; nt < 4; ++nt)
                acc[m][nt] = __builtin_amdgcn_mfma_f32_16x16x32_f16(aF[m], bF[nt][0], acc[m][nt], 0, 0, 0);
        __builtin_amdgcn_s_setprio(0);
        __builtin_amdgcn_s_barrier();

#pragma unroll
        for (int m = 0; m < 4; ++m)
            aF2[m] = *(const half8*)&smem[abase + aoff + (m + 4) * 1024 + sl0];
        if (t + 1 < NTB) STAGE_A(t + 1, 1);
        __builtin_amdgcn_s_barrier();
        asm volatile("s_waitcnt lgkmcnt(0)" ::: "memory");
        __builtin_amdgcn_s_setprio(1);
#pragma unroll
        for (int m = 0; m < 4; ++m)
#pragma unroll
            for (int nt = 0; nt < 4; ++nt)
                acc[m + 4][nt] = __builtin_amdgcn_mfma_f32_16x16x32_f16(aF2[m], bF[nt][0], acc[m + 4][nt], 0, 0, 0);
        __builtin_amdgcn_s_setprio(0);
        __builtin_amdgcn_s_barrier();

#pragma unroll
        for (int m = 0; m < 4; ++m)
            aF[m] = *(const half8*)&smem[abase + aoff + m * 1024 + (sl0 ^ 32)];
        if (t + 2 < NTB) STAGE_B(t + 2, 0);
        __builtin_amdgcn_s_barrier();
        asm volatile("s_waitcnt lgkmcnt(0)" ::: "memory");
        __builtin_amdgcn_s_setprio(1);
#pragma unroll
        for (int m = 0; m < 4; ++m)
#pragma unroll
            for (int nt = 0; nt < 4; ++nt)
                acc[m][nt] = __builtin_amdgcn_mfma_f32_16x16x32_f16(aF[m], bF[nt][1], acc[m][nt], 0, 0, 0);
        __builtin_amdgcn_s_setprio(0);
        __builtin_amdgcn_s_barrier();

#pragma unroll
        for (int m = 0; m < 4; ++m)
            aF2[m] = *(const half8*)&smem[abase + aoff + (m + 4) * 1024 + (sl0 ^ 32)];
        if (t + 2 < NTB) {
            STAGE_B(t + 2, 1);
            asm volatile("s_waitcnt vmcnt(4)" ::: "memory");
        } else {
            asm volatile("s_waitcnt vmcnt(0)" ::: "memory");
        }
        __builtin_amdgcn_s_barrier();
        asm volatile("s_waitcnt lgkmcnt(0)" ::: "memory");
        __builtin_amdgcn_s_setprio(1);
#pragma unroll
        for (int m = 0; m < 4; ++m)
#pragma unroll
            for (int nt = 0; nt < 4; ++nt)
                acc[m + 4][nt] = __builtin_amdgcn_mfma_f32_16x16x32_f16(aF2[m], bF[nt][1], acc[m + 4][nt], 0, 0, 0);
        __builtin_amdgcn_s_setprio(0);
        __builtin_amdgcn_s_barrier();
    }

    uint16_t* ob = qk + (size_t)b * SS * SS;
#pragma unroll
    for (int mt = 0; mt < 8; ++mt) {
#pragma unroll
        for (int nt = 0; nt < 4; ++nt) {
            const int srow = s0 + wm * 128 + mt * 16 + quad * 4;
            const int tcol = t0 + wn * 64 + nt * 16 + fm;
#pragma unroll
            for (int reg = 0; reg < 4; ++reg)
                ob[(size_t)(srow + reg) * SS + tcol] = f2h(acc[mt][nt][reg]);
        }
    }
}

// ---------------------------------------------------------------- rowstats
// per row of raw qk: m = max(0.125*x), l = sum exp(0.125*x - m);
// stats[row] = {m, 1/l}. Same reduction trees as softmax -> bits match.
__global__ __launch_bounds__(256) void rowstats_kernel(
    const uint16_t* __restrict__ qk, float2* __restrict__ stats)
{
    const size_t row = blockIdx.x;
    const uint16_t* x = qk + row * SS;
    const int tid  = threadIdx.x;
    const int lane = tid & 63;
    const int wave = tid >> 6;

    uintx4 raw = *(const uintx4*)(x + tid * 8);
    float v[8];
#pragma unroll
    for (int i = 0; i < 4; ++i) {
        uint32_t u = raw[i];
        v[2 * i]     = h2f(u & 0xffffu) * 0.125f;
        v[2 * i + 1] = h2f(u >> 16) * 0.125f;
    }
    float m = v[0];
#pragma unroll
    for (int j = 1; j < 8; ++j) m = fmaxf(m, v[j]);
#pragma unroll
    for (int off = 1; off < 64; off <<= 1) m = fmaxf(m, __shfl_xor(m, off, 64));
    __shared__ float red[8];
    if (lane == 0) red[wave] = m;
    __syncthreads();
    m = fmaxf(fmaxf(red[0], red[1]), fmaxf(red[2], red[3]));

    float s = 0.f;
#pragma unroll
    for (int j = 0; j < 8; ++j) s += __expf(v[j] - m);
#pragma unroll
    for (int off = 1; off < 64; off <<= 1) s += __shfl_xor(s, off, 64);
    if (lane == 0) red[4 + wave] = s;
    __syncthreads();
    s = (red[4] + red[5]) + (red[6] + red[7]);
    if (tid == 0) stats[row] = make_float2(m, 1.0f / s);
}

// ---------------------------------------------------------------- GEMM2a
// tmp[s][d] = sum_u attn[s][u] * qT[d][u], softmax fused, exp in P1.
// A: 3-buffer LDS rotation (reg-staged raw qk -> exp -> ds_write). The
// WRITE_A(t+2) exp chain runs in P1 UNDER the 12 in-flight ds_reads (no
// dependency), before the existing lgkmcnt(0). Buffer (t+2)%3 is 2 barriers
// from its last readers (P1(t-1)) -> safe. B: gload_lds double-buffer in P2.
//   P1(t): ds_read frags Abuf[t%3],Bbuf[t&1] ; LOAD_A(t+3)->regs ;
//          WRITE_A(t+2)<-cur regs ; lgkm0 ; MFMA ks0 ; bar1
//   P2(t): STAGE_B(t+2) ; vmcnt(4|2|0) ; bar2 ; MFMA ks1
// vmcnt: leaves A(t+3)regs[2]+B(t+2)[2]; forces B(t+1)+older drained.
// Math identical to R7 (verified) -> absmax must stay 0.5.
__global__ __launch_bounds__(512, 2) void gemm2a_kernel(
    const uint16_t* __restrict__ qk, const uint16_t* __restrict__ qT,
    const float2* __restrict__ stats, uint16_t* __restrict__ tmp)
{
    const int b  = blockIdx.z;
    const int s0 = blockIdx.y * 128;
    const int t0 = blockIdx.x * 128;   // d-dim tile, 0..511
    const uint16_t* ab = qk + (size_t)b * SS * SS;   // ld SS (raw scores)
    const uint16_t* bb = qT + (size_t)b * DD * SS;   // ld SS

    // halfs: Abuf0/1/2 at 0,8192,16384 ; Bbuf0/1 at 24576,32768. 80 KiB.
    __shared__ uint16_t smem[40960];

    const int tid  = threadIdx.x;
    const int lane = tid & 63;
    const int wave = tid >> 6;
    const int wm   = wave >> 2;   // 0..1 (M half: 64 rows)
    const int wn   = wave & 3;    // 0..3 (N quarter: 32 cols)
    const int fm   = lane & 15;
    const int quad = lane >> 4;

    floatx4 acc[4][2];
#pragma unroll
    for (int i = 0; i < 4; ++i)
#pragma unroll
        for (int j = 0; j < 2; ++j)
            acc[i][j] = (floatx4)0.0f;

    const int sl0  = (quad ^ (fm & 7)) * 8;           // ks0 ; ks1 -> sl0^32
    const int aoff = (wm * 64 + fm) * 64;             // + mt*1024 + slot
    const int boff = 24576 + (wn * 32 + fm) * 64;     // + nt*1024 + slot

    const int r0 = tid >> 3;                           // rows 0..63
    const int l0 = ((tid & 7) ^ (r0 & 7)) * 8;
    const int r1 = r0 + 64;                            // rows 64..127 (r1&7==r0&7)
    const int ldsW = wave * 512;

    const float2 st0 = stats[(size_t)b * SS + s0 + r0];
    const float2 st1 = stats[(size_t)b * SS + s0 + r1];

    auto LOAD_A = [&](int tt, uintx4& ua, uintx4& ub) {
        ua = *(const uintx4*)(ab + (size_t)(s0 + r0) * SS + tt * 64 + l0);
        ub = *(const uintx4*)(ab + (size_t)(s0 + r1) * SS + tt * 64 + l0);
    };
    auto WRITE_A = [&](int wbuf, const uintx4& ua, const uintx4& ub) {
        uint16_t* base = &smem[wbuf * 8192 + ldsW + lane * 8];
        PackU p;
#pragma unroll
        for (int j = 0; j < 4; ++j) {
            uint32_t u = ua[j];
            float va = h2f(u & 0xffffu) * 0.125f;
            float vb = h2f(u >> 16) * 0.125f;
            p.u[j] = pk2h(__expf(va - st0.x) * st0.y, __expf(vb - st0.x) * st0.y);
        }
        *(short8*)base = p.s8;
#pragma unroll
        for (int j = 0; j < 4; ++j) {
            uint32_t u = ub[j];
            float va = h2f(u & 0xffffu) * 0.125f;
            float vb = h2f(u >> 16) * 0.125f;
            p.u[j] = pk2h(__expf(va - st1.x) * st1.y, __expf(vb - st1.x) * st1.y);
        }
        *(short8*)(base + 4096) = p.s8;
    };
    auto STAGE_B = [&](int tt) {
        uint16_t* base = &smem[24576 + (tt & 1) * 8192 + ldsW];
        __builtin_amdgcn_global_load_lds(
            (GLOBAL_AS void*)(bb + (size_t)(t0 + r0) * SS + tt * 64 + l0),
            (LDS_AS void*)(base), 16, 0, 0);
        __builtin_amdgcn_global_load_lds(
            (GLOBAL_AS void*)(bb + (size_t)(t0 + r1) * SS + tt * 64 + l0),
            (LDS_AS void*)(base + 4096), 16, 0, 0);
    };

    // ---- prologue: A0,A1,A2 regs ; B0,B1 lds ; write A0,A1 ; full drain.
    uintx4 w0a, w0b, w1a, w1b, cur0, cur1;
    uintx4 nxt0 = {}, nxt1 = {};
    LOAD_A(0, w0a, w0b);
    LOAD_A(1, w1a, w1b);
    LOAD_A(2, cur0, cur1);
    asm volatile("" ::: "memory");
    STAGE_B(0); STAGE_B(1);
    WRITE_A(0, w0a, w0b);          // compiler inserts vmcnt for reg uses
    WRITE_A(1, w1a, w1b);
    asm volatile("s_waitcnt vmcnt(0)" ::: "memory");
    asm volatile("s_waitcnt lgkmcnt(0)" ::: "memory");
    __builtin_amdgcn_s_barrier();

    half8 aF[4][2], bF[2][2];
    int rdA = 0, wrA = 2;

    for (int t = 0; t < NT2A; ++t) {
        const int abase = rdA * 8192;
        const int bbase = (t & 1) * 8192;

        // ===== P1: ds_read tile t ; LOAD_A(t+3) ; WRITE_A(t+2) ; MFMA ks0
#pragma unroll
        for (int m = 0; m < 4; ++m) {
            aF[m][0] = *(const half8*)&smem[abase + aoff + m * 1024 + sl0];
            aF[m][1] = *(const half8*)&smem[abase + aoff + m * 1024 + (sl0 ^ 32)];
        }
#pragma unroll
        for (int n = 0; n < 2; ++n) {
            bF[n][0] = *(const half8*)&smem[bbase + boff + n * 1024 + sl0];
            bF[n][1] = *(const half8*)&smem[bbase + boff + n * 1024 + (sl0 ^ 32)];
        }
        if (t + 3 < NT2A) LOAD_A(t + 3, nxt0, nxt1);
        if (t + 2 < NT2A) WRITE_A(wrA, cur0, cur1);   // exp overlaps ds_reads
        asm volatile("s_waitcnt lgkmcnt(0)" ::: "memory");
        __builtin_amdgcn_s_setprio(1);
#pragma unroll
        for (int m = 0; m < 4; ++m)
#pragma unroll
            for (int n = 0; n < 2; ++n)
                acc[m][n] = __builtin_amdgcn_mfma_f32_16x16x32_f16(aF[m][0], bF[n][0], acc[m][n], 0, 0, 0);
        __builtin_amdgcn_s_setprio(0);
        __builtin_amdgcn_s_barrier();   // bar1

        // ===== P2: B(t+2) ; counted vmcnt ; bar2 ; MFMA ks1
        if (t + 2 < NT2A) {
            STAGE_B(t + 2);
            if (t + 3 < NT2A) {
                asm volatile("s_waitcnt vmcnt(4)" ::: "memory");
            } else {
                asm volatile("s_waitcnt vmcnt(2)" ::: "memory");
            }
        } else {
            asm volatile("s_waitcnt vmcnt(0)" ::: "memory");
        }
        __builtin_amdgcn_s_barrier();   // bar2
        __builtin_amdgcn_s_setprio(1);
#pragma unroll
        for (int m = 0; m < 4; ++m)
#pragma unroll
            for (int n = 0; n < 2; ++n)
                acc[m][n] = __builtin_amdgcn_mfma_f32_16x16x32_f16(aF[m][1], bF[n][1], acc[m][n], 0, 0, 0);
        __builtin_amdgcn_s_setprio(0);

        cur0 = nxt0; cur1 = nxt1;
        rdA = (rdA == 2) ? 0 : rdA + 1;
        wrA = (wrA == 2) ? 0 : wrA + 1;
    }

    uint16_t* tb = tmp + (size_t)b * SS * DD;
#pragma unroll
    for (int mt = 0; mt < 4; ++mt) {
#pragma unroll
        for (int n = 0; n < 2; ++n) {
            const int srw  = s0 + wm * 64 + mt * 16 + quad * 4;
            const int tcol = t0 + wn * 32 + n * 16 + fm;
#pragma unroll
            for (int reg = 0; reg < 4; ++reg)
                tb[(size_t)(srw + reg) * DD + tcol] = f2h(acc[mt][n][reg]);
        }
    }
}

// ---------------------------------------------------------------- GEMM2b
// out[s][t] = sum_d tmp[s][d] * kH[t][d]  (f16, 256^2 8-phase, f32 out)
__global__ __launch_bounds__(512, 2) void gemm2b_kernel(
    const uint16_t* __restrict__ tmp, const uint16_t* __restrict__ kH,
    float* __restrict__ out)
{
    const int b  = blockIdx.z;
    const int s0 = blockIdx.y * 256;
    const int t0 = blockIdx.x * 256;
    const uint16_t* ab = tmp + (size_t)b * SS * DD;
    const uint16_t* bb = kH  + (size_t)b * SS * DD;

    __shared__ uint16_t smem[65536];

    const int tid  = threadIdx.x;
    const int lane = tid & 63;
    const int wave = tid >> 6;
    const int wm   = wave >> 2;
    const int wn   = wave & 3;
    const int fm   = lane & 15;
    const int quad = lane >> 4;

    floatx4 acc[8][4];
#pragma unroll
    for (int i = 0; i < 8; ++i)
#pragma unroll
        for (int j = 0; j < 4; ++j)
            acc[i][j] = (floatx4)0.0f;

    const int sl0  = (quad ^ (fm & 7)) * 8;
    const int aoff = (wm * 128 + fm) * 64;
    const int boff = 32768 + (wn * 64 + fm) * 64;

    const int c0 = wave * 128 + lane;
    const int r0 = c0 >> 3;  const int l0 = ((c0 & 7) ^ (r0 & 7)) * 8;
    const int c1 = c0 + 64;
    const int r1 = c1 >> 3;  const int l1 = ((c1 & 7) ^ (r1 & 7)) * 8;
    const int ldsW = wave * 1024;

    auto STAGE_A = [&](int tt, int h) {
        uint16_t* base = &smem[(tt & 1) * 16384 + h * 8192 + ldsW];
        __builtin_amdgcn_global_load_lds(
            (GLOBAL_AS void*)(ab + (size_t)(s0 + h * 128 + r0) * DD + tt * 64 + l0),
            (LDS_AS void*)(base), 16, 0, 0);
        __builtin_amdgcn_global_load_lds(
            (GLOBAL_AS void*)(ab + (size_t)(s0 + h * 128 + r1) * DD + tt * 64 + l1),
            (LDS_AS void*)(base + 512), 16, 0, 0);
    };
    auto STAGE_B = [&](int tt, int h) {
        uint16_t* base = &smem[32768 + (tt & 1) * 16384 + h * 8192 + ldsW];
        __builtin_amdgcn_global_load_lds(
            (GLOBAL_AS void*)(bb + (size_t)(t0 + h * 128 + r0) * DD + tt * 64 + l0),
            (LDS_AS void*)(base), 16, 0, 0);
        __builtin_amdgcn_global_load_lds(
            (GLOBAL_AS void*)(bb + (size_t)(t0 + h * 128 + r1) * DD + tt * 64 + l1),
            (LDS_AS void*)(base + 512), 16, 0, 0);
    };

    STAGE_A(0, 0); STAGE_A(0, 1); STAGE_B(0, 0); STAGE_B(0, 1);
    STAGE_B(1, 0); STAGE_B(1, 1);
    asm volatile("s_waitcnt vmcnt(4)" ::: "memory");
    __builtin_amdgcn_s_barrier();

    half8 aF[4], aF2[4], bF[4][2];

    for (int t = 0; t < NTB; ++t) {
        const int abase = (t & 1) * 16384;
        const int bbase = (t & 1) * 16384;

#pragma unroll
        for (int nt = 0; nt < 4; ++nt) {
            bF[nt][0] = *(const half8*)&smem[bbase + boff + nt * 1024 + sl0];
            bF[nt][1] = *(const half8*)&smem[bbase + boff + nt * 1024 + (sl0 ^ 32)];
        }
#pragma unroll
        for (int m = 0; m < 4; ++m)
            aF[m] = *(const half8*)&smem[abase + aoff + m * 1024 + sl0];
        if (t + 1 < NTB) STAGE_A(t + 1, 0);
        __builtin_amdgcn_s_barrier();
        asm volatile("s_waitcnt lgkmcnt(0)" ::: "memory");
        __builtin_amdgcn_s_setprio(1);
#pragma unroll
        for (int m = 0; m < 4; ++m)
#pragma unroll
            for (int nt = 0; nt < 4; ++nt)
                acc[m][nt] = __builtin_amdgcn_mfma_f32_16x16x32_f16(aF[m], bF[nt][0], acc[m][nt], 0, 0, 0);
        __builtin_amdgcn_s_setprio(0);
        __builtin_amdgcn_s_barrier();

#pragma unroll
        for (int m = 0; m < 4; ++m)
            aF2[m] = *(const half8*)&smem[abase + aoff + (m + 4) * 1024 + sl0];
        if (t + 1 < NTB) STAGE_A(t + 1, 1);
        __builtin_amdgcn_s_barrier();
        asm volatile("s_waitcnt lgkmcnt(0)" ::: "memory");
        __builtin_amdgcn_s_setprio(1);
#pragma unroll
        for (int m = 0; m < 4; ++m)
#pragma unroll
            for (int nt = 0; nt < 4; ++nt)
                acc[m + 4][nt] = __builtin_amdgcn_mfma_f32_16x16x32_f16(aF2[m], bF[nt][0], acc[m + 4][nt], 0, 0, 0);
        __builtin_amdgcn_s_setprio(0);
        __builtin_amdgcn_s_barrier();

#pragma unroll
        for (int m = 0; m < 4; ++m)
            aF[m] = *(const half8*)&smem[abase + aoff + m * 1024 + (sl0 ^ 32)];
        if (t + 2 < NTB) STAGE_B(t + 2, 0);
        __builtin_amdgcn_s_barrier();
        asm volatile("s_waitcnt lgkmcnt(0)" ::: "memory");
        __builtin_amdgcn_s_setprio(1);
#pragma unroll
        for (int m = 0; m < 4; ++m)
#pragma unroll
            for (int nt = 0; nt < 4; ++nt)
                acc[m][nt] = __builtin_amdgcn_mfma_f32_16x16x32_f16(aF[m], bF[nt][1], acc[m][nt], 0, 0, 0);
        __builtin_amdgcn_s_setprio(0);
        __builtin_amdgcn_s_barrier();

#pragma unroll
        for (int m = 0; m < 4; ++m)
            aF2[m] = *(const half8*)&smem[abase + aoff + (m + 4) * 1024 + (sl0 ^ 32)];
        if (t + 2 < NTB) {
            STAGE_B(t + 2, 1);
            asm volatile("s_waitcnt vmcnt(4)" ::: "memory");
        } else {
            asm volatile("s_waitcnt vmcnt(0)" ::: "memory");
        }
        __builtin_amdgcn_s_barrier();
        asm volatile("s_waitcnt lgkmcnt(0)" ::: "memory");
        __builtin_amdgcn_s_setprio(1);
#pragma unroll
        for (int m = 0; m < 4; ++m)
#pragma unroll
            for (int nt = 0; nt < 4; ++nt)
                acc[m + 4][nt] = __builtin_amdgcn_mfma_f32_16x16x32_f16(aF2[m], bF[nt][1], acc[m + 4][nt], 0, 0, 0);
        __builtin_amdgcn_s_setprio(0);
        __builtin_amdgcn_s_barrier();
    }

    float* ob = out + (size_t)b * SS * SS;
#pragma unroll
    for (int mt = 0; mt < 8; ++mt) {
#pragma unroll
        for (int nt = 0; nt < 4; ++nt) {
            const int srow = s0 + wm * 128 + mt * 16 + quad * 4;
            const int tcol = t0 + wn * 64 + nt * 16 + fm;
#pragma unroll
            for (int reg = 0; reg < 4; ++reg)
                ob[(size_t)(srow + reg) * SS + tcol] = acc[mt][nt][reg];
        }
    }
}

extern "C" void kernel_launch(void* const* d_in, const int* in_sizes, int n_in,
                              void* d_out, int out_size, void* d_ws, size_t ws_size,
                              hipStream_t stream) {
    const float* q = (const float*)d_in[0];
    const float* k = (const float*)d_in[1];
    float* out = (float*)d_out;

    uint16_t* qk  = (uint16_t*)d_ws;                   // 4*2048*2048
    uint16_t* qT  = qk + (size_t)BATCH * SS * SS;      // 4*512*2048
    uint16_t* qH  = qT + (size_t)BATCH * DD * SS;      // 4*2048*512
    uint16_t* kH  = qH + (size_t)BATCH * SS * DD;      // 4*2048*512
    uint16_t* tmp = kH + (size_t)BATCH * SS * DD;      // 4*2048*512
    float2* stats = (float2*)(tmp + (size_t)BATCH * SS * DD);  // 4*2048 pairs

    prep_kernel<<<dim3(32, 9, BATCH), 256, 0, stream>>>(q, k, qT, qH, kH);
    gemm1_kernel<<<dim3(SS / 256, SS / 256, BATCH), 512, 0, stream>>>(qH, kH, qk);
    rowstats_kernel<<<dim3(BATCH * SS), 256, 0, stream>>>(qk, stats);
    gemm2a_kernel<<<dim3(DD / 128, SS / 128, BATCH), 512, 0, stream>>>(qk, qT, stats, tmp);
    gemm2b_kernel<<<dim3(SS / 256, SS / 256, BATCH), 512, 0, stream>>>(tmp, kH, out);
}

// Round 9
// 185.938 us; speedup vs baseline: 1.0993x; 1.0703x over previous
//
#include <hip/hip_runtime.h>
#include <hip/hip_bf16.h>
#include <stdint.h>

// Re-associated pipeline, all-f16 intermediates:
//   prep : qT=f16(q^T) + qH=f16(q) (ONE q read) | kH=f16(k)   [streaming]
//   gemm1: qk = qH @ kH^T  (f16 MFMA, 256^2 8-phase)          [qk f16]
//   softmax: attn = softmax(0.125*qk) in-place                [f16]
//   gemm2a: tmp = attn @ qT^T  (f16, 128^2 2-phase pipelined) [tmp f16]
//   gemm2b: out = tmp @ kH^T   (f16, 256^2 8-phase, f32 out)
// Round 10: REVERT the softmax-fusion experiment (R7/R8). Measured verdict:
// fused exp costs +20us VALU in gemm2a vs -6us net HBM saved (gemm2a has
// only 8 MFMAs/phase to hide 16-exp chains under). Back to R6's verified
// separate softmax + 24us gemm2a; KEEP R8's single-q-read prep (-67MB HBM).
// All components previously bit-verified -> absmax must stay 0.5.

#define SS 2048
#define DD 512
#define BATCH 4
#define NTB 8    // K tiles of 64 for K=512 (gemm1, gemm2b)
#define NT2A 32  // K tiles of 64 for K=2048 (gemm2a)

typedef __attribute__((ext_vector_type(8))) short short8;
typedef __attribute__((ext_vector_type(8))) _Float16 half8;
typedef __attribute__((ext_vector_type(4))) float floatx4;
typedef __attribute__((ext_vector_type(4))) float float4v;
typedef __attribute__((ext_vector_type(4))) unsigned int uintx4;

#define GLOBAL_AS const __attribute__((address_space(1)))
#define LDS_AS __attribute__((address_space(3)))

__device__ __forceinline__ uint32_t pk2h(float x, float y) {
    _Float16 hx = (_Float16)x, hy = (_Float16)y;   // RNE v_cvt_f16_f32
    union { _Float16 h; uint16_t u; } cx, cy;
    cx.h = hx; cy.h = hy;
    return (uint32_t)cx.u | ((uint32_t)cy.u << 16);
}
__device__ __forceinline__ float h2f(uint32_t ubits) {
    union { uint16_t u; _Float16 h; } c; c.u = (uint16_t)ubits; return (float)c.h;
}
__device__ __forceinline__ uint16_t f2h(float f) {
    union { _Float16 h; uint16_t u; } c; c.h = (_Float16)f; return c.u;
}

union PackU { uint32_t u[4]; short8 s8; };

// ---------------------------------------------------------------- prep
// y<8 : qT[b][d][u] = f16(q[b][u][d])  AND qH[b][u][d] (q read once)
// y==8: kH[b][t][d] = f16(k[b][t][d])
__global__ __launch_bounds__(256) void prep_kernel(
    const float* __restrict__ Q, const float* __restrict__ K,
    uint16_t* __restrict__ qT, uint16_t* __restrict__ qH,
    uint16_t* __restrict__ kH)
{
    const int b   = blockIdx.z;
    const int tid = threadIdx.x;

    if (blockIdx.y == 8) {
        const float* src = K + (size_t)b * SS * DD;
        uint16_t* dst = kH + (size_t)b * SS * DD;
        const int g0 = blockIdx.x * 256 + tid;
#pragma unroll
        for (int i = 0; i < 16; ++i) {
            const int g = g0 + i * 8192;
            const float4v* s4 = (const float4v*)(src + (size_t)g * 8);
            float4v x0 = s4[0], x1 = s4[1];
            PackU p;
            p.u[0] = pk2h(x0[0], x0[1]);
            p.u[1] = pk2h(x0[2], x0[3]);
            p.u[2] = pk2h(x1[0], x1[1]);
            p.u[3] = pk2h(x1[2], x1[3]);
            *(short8*)(dst + (size_t)g * 8) = p.s8;
        }
        return;
    }

    const int u0 = blockIdx.x * 64;
    const int d0 = blockIdx.y * 64;
    const float* qb = Q + (size_t)b * SS * DD;
    uint16_t* qTb = qT + (size_t)b * DD * SS;
    uint16_t* qHb = qH + (size_t)b * SS * DD;

    __shared__ uint16_t T[64 * 66];

    {
        const int r  = tid >> 2;
        const int c4 = (tid & 3) * 16;
        const float* src = qb + (size_t)(u0 + r) * DD + d0 + c4;
        float4v x0 = *(const float4v*)(src + 0);
        float4v x1 = *(const float4v*)(src + 4);
        float4v x2 = *(const float4v*)(src + 8);
        float4v x3 = *(const float4v*)(src + 12);
        uint32_t w0 = pk2h(x0[0], x0[1]), w1 = pk2h(x0[2], x0[3]);
        uint32_t w2 = pk2h(x1[0], x1[1]), w3 = pk2h(x1[2], x1[3]);
        uint32_t w4 = pk2h(x2[0], x2[1]), w5 = pk2h(x2[2], x2[3]);
        uint32_t w6 = pk2h(x3[0], x3[1]), w7 = pk2h(x3[2], x3[3]);
        uint32_t* tw = (uint32_t*)&T[r * 66 + c4];
        tw[0] = w0; tw[1] = w1; tw[2] = w2; tw[3] = w3;
        tw[4] = w4; tw[5] = w5; tw[6] = w6; tw[7] = w7;
        PackU p;
        p.u[0] = w0; p.u[1] = w1; p.u[2] = w2; p.u[3] = w3;
        *(short8*)(&qHb[(size_t)(u0 + r) * DD + d0 + c4]) = p.s8;
        p.u[0] = w4; p.u[1] = w5; p.u[2] = w6; p.u[3] = w7;
        *(short8*)(&qHb[(size_t)(u0 + r) * DD + d0 + c4 + 8]) = p.s8;
    }
    __syncthreads();
#pragma unroll
    for (int p = 0; p < 2; ++p) {
        const int dl  = (tid >> 3) + p * 32;
        const int ul8 = (tid & 7) * 8;
        uint16_t t8[8];
#pragma unroll
        for (int j = 0; j < 8; ++j) t8[j] = T[(ul8 + j) * 66 + dl];
        PackU o;
        o.u[0] = (uint32_t)t8[0] | ((uint32_t)t8[1] << 16);
        o.u[1] = (uint32_t)t8[2] | ((uint32_t)t8[3] << 16);
        o.u[2] = (uint32_t)t8[4] | ((uint32_t)t8[5] << 16);
        o.u[3] = (uint32_t)t8[6] | ((uint32_t)t8[7] << 16);
        *(short8*)(&qTb[(size_t)(d0 + dl) * SS + u0 + ul8]) = o.s8;
    }
}

// ---------------------------------------------------------------- GEMM1
// qk[s][t] = sum_d qH[s][d]*kH[t][d] — 256^2 8-phase f16, NTB=8, f16 out.
__global__ __launch_bounds__(512, 2) void gemm1_kernel(
    const uint16_t* __restrict__ qH, const uint16_t* __restrict__ kH,
    uint16_t* __restrict__ qk)
{
    const int b  = blockIdx.z;
    const int s0 = blockIdx.y * 256;
    const int t0 = blockIdx.x * 256;
    const uint16_t* ab = qH + (size_t)b * SS * DD;
    const uint16_t* bb = kH + (size_t)b * SS * DD;

    __shared__ uint16_t smem[65536];

    const int tid  = threadIdx.x;
    const int lane = tid & 63;
    const int wave = tid >> 6;
    const int wm   = wave >> 2;
    const int wn   = wave & 3;
    const int fm   = lane & 15;
    const int quad = lane >> 4;

    floatx4 acc[8][4];
#pragma unroll
    for (int i = 0; i < 8; ++i)
#pragma unroll
        for (int j = 0; j < 4; ++j)
            acc[i][j] = (floatx4)0.0f;

    const int sl0  = (quad ^ (fm & 7)) * 8;
    const int aoff = (wm * 128 + fm) * 64;
    const int boff = 32768 + (wn * 64 + fm) * 64;

    const int c0 = wave * 128 + lane;
    const int r0 = c0 >> 3;  const int l0 = ((c0 & 7) ^ (r0 & 7)) * 8;
    const int c1 = c0 + 64;
    const int r1 = c1 >> 3;  const int l1 = ((c1 & 7) ^ (r1 & 7)) * 8;
    const int ldsW = wave * 1024;

    auto STAGE_A = [&](int tt, int h) {
        uint16_t* base = &smem[(tt & 1) * 16384 + h * 8192 + ldsW];
        __builtin_amdgcn_global_load_lds(
            (GLOBAL_AS void*)(ab + (size_t)(s0 + h * 128 + r0) * DD + tt * 64 + l0),
            (LDS_AS void*)(base), 16, 0, 0);
        __builtin_amdgcn_global_load_lds(
            (GLOBAL_AS void*)(ab + (size_t)(s0 + h * 128 + r1) * DD + tt * 64 + l1),
            (LDS_AS void*)(base + 512), 16, 0, 0);
    };
    auto STAGE_B = [&](int tt, int h) {
        uint16_t* base = &smem[32768 + (tt & 1) * 16384 + h * 8192 + ldsW];
        __builtin_amdgcn_global_load_lds(
            (GLOBAL_AS void*)(bb + (size_t)(t0 + h * 128 + r0) * DD + tt * 64 + l0),
            (LDS_AS void*)(base), 16, 0, 0);
        __builtin_amdgcn_global_load_lds(
            (GLOBAL_AS void*)(bb + (size_t)(t0 + h * 128 + r1) * DD + tt * 64 + l1),
            (LDS_AS void*)(base + 512), 16, 0, 0);
    };

    STAGE_A(0, 0); STAGE_A(0, 1); STAGE_B(0, 0); STAGE_B(0, 1);
    STAGE_B(1, 0); STAGE_B(1, 1);
    asm volatile("s_waitcnt vmcnt(4)" ::: "memory");
    __builtin_amdgcn_s_barrier();

    half8 aF[4], aF2[4], bF[4][2];

    for (int t = 0; t < NTB; ++t) {
        const int abase = (t & 1) * 16384;
        const int bbase = (t & 1) * 16384;

#pragma unroll
        for (int nt = 0; nt < 4; ++nt) {
            bF[nt][0] = *(const half8*)&smem[bbase + boff + nt * 1024 + sl0];
            bF[nt][1] = *(const half8*)&smem[bbase + boff + nt * 1024 + (sl0 ^ 32)];
        }
#pragma unroll
        for (int m = 0; m < 4; ++m)
            aF[m] = *(const half8*)&smem[abase + aoff + m * 1024 + sl0];
        if (t + 1 < NTB) STAGE_A(t + 1, 0);
        __builtin_amdgcn_s_barrier();
        asm volatile("s_waitcnt lgkmcnt(0)" ::: "memory");
        __builtin_amdgcn_s_setprio(1);
#pragma unroll
        for (int m = 0; m < 4; ++m)
#pragma unroll
            for (int nt = 0; nt < 4; ++nt)
                acc[m][nt] = __builtin_amdgcn_mfma_f32_16x16x32_f16(aF[m], bF[nt][0], acc[m][nt], 0, 0, 0);
        __builtin_amdgcn_s_setprio(0);
        __builtin_amdgcn_s_barrier();

#pragma unroll
        for (int m = 0; m < 4; ++m)
            aF2[m] = *(const half8*)&smem[abase + aoff + (m + 4) * 1024 + sl0];
        if (t + 1 < NTB) STAGE_A(t + 1, 1);
        __builtin_amdgcn_s_barrier();
        asm volatile("s_waitcnt lgkmcnt(0)" ::: "memory");
        __builtin_amdgcn_s_setprio(1);
#pragma unroll
        for (int m = 0; m < 4; ++m)
#pragma unroll
            for (int nt = 0; nt < 4; ++nt)
                acc[m + 4][nt] = __builtin_amdgcn_mfma_f32_16x16x32_f16(aF2[m], bF[nt][0], acc[m + 4][nt], 0, 0, 0);
        __builtin_amdgcn_s_setprio(0);
        __builtin_amdgcn_s_barrier();

#pragma unroll
        for (int m = 0; m < 4; ++m)
            aF[m] = *(const half8*)&smem[abase + aoff + m * 1024 + (sl0 ^ 32)];
        if (t + 2 < NTB) STAGE_B(t + 2, 0);
        __builtin_amdgcn_s_barrier();
        asm volatile("s_waitcnt lgkmcnt(0)" ::: "memory");
        __builtin_amdgcn_s_setprio(1);
#pragma unroll
        for (int m = 0; m < 4; ++m)
#pragma unroll
            for (int nt = 0; nt < 4; ++nt)
                acc[m][nt] = __builtin_amdgcn_mfma_f32_16x16x32_f16(aF[m], bF[nt][1], acc[m][nt], 0, 0, 0);
        __builtin_amdgcn_s_setprio(0);
        __builtin_amdgcn_s_barrier();

#pragma unroll
        for (int m = 0; m < 4; ++m)
            aF2[m] = *(const half8*)&smem[abase + aoff + (m + 4) * 1024 + (sl0 ^ 32)];
        if (t + 2 < NTB) {
            STAGE_B(t + 2, 1);
            asm volatile("s_waitcnt vmcnt(4)" ::: "memory");
        } else {
            asm volatile("s_waitcnt vmcnt(0)" ::: "memory");
        }
        __builtin_amdgcn_s_barrier();
        asm volatile("s_waitcnt lgkmcnt(0)" ::: "memory");
        __builtin_amdgcn_s_setprio(1);
#pragma unroll
        for (int m = 0; m < 4; ++m)
#pragma unroll
            for (int nt = 0; nt < 4; ++nt)
                acc[m + 4][nt] = __builtin_amdgcn_mfma_f32_16x16x32_f16(aF2[m], bF[nt][1], acc[m + 4][nt], 0, 0, 0);
        __builtin_amdgcn_s_setprio(0);
        __builtin_amdgcn_s_barrier();
    }

    uint16_t* ob = qk + (size_t)b * SS * SS;
#pragma unroll
    for (int mt = 0; mt < 8; ++mt) {
#pragma unroll
        for (int nt = 0; nt < 4; ++nt) {
            const int srow = s0 + wm * 128 + mt * 16 + quad * 4;
            const int tcol = t0 + wn * 64 + nt * 16 + fm;
#pragma unroll
            for (int reg = 0; reg < 4; ++reg)
                ob[(size_t)(srow + reg) * SS + tcol] = f2h(acc[mt][nt][reg]);
        }
    }
}

// ---------------------------------------------------------------- softmax
// in-place: qk row (f16) -> softmax(0.125*row), f16.
__global__ __launch_bounds__(256) void softmax_inplace(uint16_t* __restrict__ qk)
{
    const size_t row = blockIdx.x;
    uint16_t* x = qk + row * SS;
    const int tid  = threadIdx.x;
    const int lane = tid & 63;
    const int wave = tid >> 6;

    uintx4 raw = *(const uintx4*)(x + tid * 8);
    float v[8];
#pragma unroll
    for (int i = 0; i < 4; ++i) {
        uint32_t u = raw[i];
        v[2 * i]     = h2f(u & 0xffffu) * 0.125f;
        v[2 * i + 1] = h2f(u >> 16) * 0.125f;
    }
    float m = v[0];
#pragma unroll
    for (int j = 1; j < 8; ++j) m = fmaxf(m, v[j]);
#pragma unroll
    for (int off = 1; off < 64; off <<= 1) m = fmaxf(m, __shfl_xor(m, off, 64));
    __shared__ float red[8];
    if (lane == 0) red[wave] = m;
    __syncthreads();
    m = fmaxf(fmaxf(red[0], red[1]), fmaxf(red[2], red[3]));

    float s = 0.f;
#pragma unroll
    for (int j = 0; j < 8; ++j) { v[j] = __expf(v[j] - m); s += v[j]; }
#pragma unroll
    for (int off = 1; off < 64; off <<= 1) s += __shfl_xor(s, off, 64);
    if (lane == 0) red[4 + wave] = s;
    __syncthreads();
    s = (red[4] + red[5]) + (red[6] + red[7]);
    const float inv = 1.0f / s;
#pragma unroll
    for (int i = 0; i < 4; ++i)
        raw[i] = pk2h(v[2 * i] * inv, v[2 * i + 1] * inv);
    *(uintx4*)(x + tid * 8) = raw;
}

// ---------------------------------------------------------------- GEMM2a
// tmp[s][d] = sum_u attn[s][u] * qT[d][u]  (M=2048, N=512, K=2048), f16.
// 128x128 tile, 512 thr / 8 waves (2M x 4N), per-wave 64x32 output.
// 2-phase counted-vmcnt pipeline, distance-2 prefetch both operands.
// Full tile = 1024 x 16B chunks; each thread stages 2 chunks per operand
// (tid and tid+512) -> 4 gload_lds per tile; vmcnt(4) steady state.
//   P1: ds_read all 12 frags of tile t ; lgkm0 ; MFMA ks0 ; bar1
//   P2: STAGE A(t+2),B(t+2) (same buf as t, safe after bar1) ; vmcnt(4)
//       (t+1 landed) ; bar2 ; MFMA ks1
// Verified in R6 (absmax 0.5, ~24us).
__global__ __launch_bounds__(512, 2) void gemm2a_kernel(
    const uint16_t* __restrict__ attn, const uint16_t* __restrict__ qT,
    uint16_t* __restrict__ tmp)
{
    const int b  = blockIdx.z;
    const int s0 = blockIdx.y * 128;
    const int t0 = blockIdx.x * 128;   // d-dim tile, 0..511
    const uint16_t* ab = attn + (size_t)b * SS * SS;   // ld SS
    const uint16_t* bb = qT   + (size_t)b * DD * SS;   // ld SS

    // halfs: Abuf0 [0,8192) Abuf1 [8192,16384) Bbuf0 [16384,24576) Bbuf1 [24576,32768)
    __shared__ uint16_t smem[32768];   // 64 KiB

    const int tid  = threadIdx.x;
    const int lane = tid & 63;
    const int wave = tid >> 6;
    const int wm   = wave >> 2;   // 0..1 (M half: 64 rows)
    const int wn   = wave & 3;    // 0..3 (N quarter: 32 cols)
    const int fm   = lane & 15;
    const int quad = lane >> 4;

    floatx4 acc[4][2];
#pragma unroll
    for (int i = 0; i < 4; ++i)
#pragma unroll
        for (int j = 0; j < 2; ++j)
            acc[i][j] = (floatx4)0.0f;

    // swizzled read addressing: tile [128 rows][8 slots of 8 halfs]
    const int sl0  = (quad ^ (fm & 7)) * 8;           // ks0 ; ks1 -> sl0^32
    const int aoff = (wm * 64 + fm) * 64;             // + mt*1024 + slot
    const int boff = 16384 + (wn * 32 + fm) * 64;     // + nt*1024 + slot

    // staging: tile = 1024 chunks of 16B; thread stages chunks tid and tid+512.
    const int r0 = tid >> 3;                           // rows 0..63
    const int l0 = (((tid & 7) ^ (r0 & 7))) * 8;
    const int r1 = r0 + 64;                            // rows 64..127
    const int l1 = l0;                                 // r1&7 == r0&7
    const int ldsW = wave * 512;

    auto STAGE_A = [&](int tt) {
        uint16_t* base = &smem[(tt & 1) * 8192 + ldsW];
        __builtin_amdgcn_global_load_lds(
            (GLOBAL_AS void*)(ab + (size_t)(s0 + r0) * SS + tt * 64 + l0),
            (LDS_AS void*)(base), 16, 0, 0);
        __builtin_amdgcn_global_load_lds(
            (GLOBAL_AS void*)(ab + (size_t)(s0 + r1) * SS + tt * 64 + l1),
            (LDS_AS void*)(base + 4096), 16, 0, 0);
    };
    auto STAGE_B = [&](int tt) {
        uint16_t* base = &smem[16384 + (tt & 1) * 8192 + ldsW];
        __builtin_amdgcn_global_load_lds(
            (GLOBAL_AS void*)(bb + (size_t)(t0 + r0) * SS + tt * 64 + l0),
            (LDS_AS void*)(base), 16, 0, 0);
        __builtin_amdgcn_global_load_lds(
            (GLOBAL_AS void*)(bb + (size_t)(t0 + r1) * SS + tt * 64 + l1),
            (LDS_AS void*)(base + 4096), 16, 0, 0);
    };

    // prologue: tiles 0,1 in flight (8 loads); wait tile 0 (leave tile 1's 4)
    STAGE_A(0); STAGE_B(0); STAGE_A(1); STAGE_B(1);
    asm volatile("s_waitcnt vmcnt(4)" ::: "memory");
    __builtin_amdgcn_s_barrier();

    half8 aF[4][2], bF[2][2];

    for (int t = 0; t < NT2A; ++t) {
        const int buf = (t & 1) * 8192;

        // ===== P1: read all 12 frags of tile t ; MFMA ks0
#pragma unroll
        for (int m = 0; m < 4; ++m) {
            aF[m][0] = *(const half8*)&smem[buf + aoff + m * 1024 + sl0];
            aF[m][1] = *(const half8*)&smem[buf + aoff + m * 1024 + (sl0 ^ 32)];
        }
#pragma unroll
        for (int n = 0; n < 2; ++n) {
            bF[n][0] = *(const half8*)&smem[buf + boff + n * 1024 + sl0];
            bF[n][1] = *(const half8*)&smem[buf + boff + n * 1024 + (sl0 ^ 32)];
        }
        asm volatile("s_waitcnt lgkmcnt(0)" ::: "memory");
        __builtin_amdgcn_s_setprio(1);
#pragma unroll
        for (int m = 0; m < 4; ++m)
#pragma unroll
            for (int n = 0; n < 2; ++n)
                acc[m][n] = __builtin_amdgcn_mfma_f32_16x16x32_f16(aF[m][0], bF[n][0], acc[m][n], 0, 0, 0);
        __builtin_amdgcn_s_setprio(0);
        __builtin_amdgcn_s_barrier();   // bar1: all waves done reading tile t

        // ===== P2: stage t+2 (same buffer as t; safe after bar1) ; MFMA ks1
        if (t + 2 < NT2A) {
            STAGE_A(t + 2); STAGE_B(t + 2);
            asm volatile("s_waitcnt vmcnt(4)" ::: "memory");   // t+1 landed
        } else {
            asm volatile("s_waitcnt vmcnt(0)" ::: "memory");
        }
        __builtin_amdgcn_s_barrier();   // bar2: t+1 resident for every wave
        __builtin_amdgcn_s_setprio(1);
#pragma unroll
        for (int m = 0; m < 4; ++m)
#pragma unroll
            for (int n = 0; n < 2; ++n)
                acc[m][n] = __builtin_amdgcn_mfma_f32_16x16x32_f16(aF[m][1], bF[n][1], acc[m][n], 0, 0, 0);
        __builtin_amdgcn_s_setprio(0);
    }

    uint16_t* tb = tmp + (size_t)b * SS * DD;
#pragma unroll
    for (int mt = 0; mt < 4; ++mt) {
#pragma unroll
        for (int n = 0; n < 2; ++n) {
            const int srw  = s0 + wm * 64 + mt * 16 + quad * 4;
            const int tcol = t0 + wn * 32 + n * 16 + fm;
#pragma unroll
            for (int reg = 0; reg < 4; ++reg)
                tb[(size_t)(srw + reg) * DD + tcol] = f2h(acc[mt][n][reg]);
        }
    }
}

// ---------------------------------------------------------------- GEMM2b
// out[s][t] = sum_d tmp[s][d] * kH[t][d]  (f16, 256^2 8-phase, f32 out)
__global__ __launch_bounds__(512, 2) void gemm2b_kernel(
    const uint16_t* __restrict__ tmp, const uint16_t* __restrict__ kH,
    float* __restrict__ out)
{
    const int b  = blockIdx.z;
    const int s0 = blockIdx.y * 256;
    const int t0 = blockIdx.x * 256;
    const uint16_t* ab = tmp + (size_t)b * SS * DD;
    const uint16_t* bb = kH  + (size_t)b * SS * DD;

    __shared__ uint16_t smem[65536];

    const int tid  = threadIdx.x;
    const int lane = tid & 63;
    const int wave = tid >> 6;
    const int wm   = wave >> 2;
    const int wn   = wave & 3;
    const int fm   = lane & 15;
    const int quad = lane >> 4;

    floatx4 acc[8][4];
#pragma unroll
    for (int i = 0; i < 8; ++i)
#pragma unroll
        for (int j = 0; j < 4; ++j)
            acc[i][j] = (floatx4)0.0f;

    const int sl0  = (quad ^ (fm & 7)) * 8;
    const int aoff = (wm * 128 + fm) * 64;
    const int boff = 32768 + (wn * 64 + fm) * 64;

    const int c0 = wave * 128 + lane;
    const int r0 = c0 >> 3;  const int l0 = ((c0 & 7) ^ (r0 & 7)) * 8;
    const int c1 = c0 + 64;
    const int r1 = c1 >> 3;  const int l1 = ((c1 & 7) ^ (r1 & 7)) * 8;
    const int ldsW = wave * 1024;

    auto STAGE_A = [&](int tt, int h) {
        uint16_t* base = &smem[(tt & 1) * 16384 + h * 8192 + ldsW];
        __builtin_amdgcn_global_load_lds(
            (GLOBAL_AS void*)(ab + (size_t)(s0 + h * 128 + r0) * DD + tt * 64 + l0),
            (LDS_AS void*)(base), 16, 0, 0);
        __builtin_amdgcn_global_load_lds(
            (GLOBAL_AS void*)(ab + (size_t)(s0 + h * 128 + r1) * DD + tt * 64 + l1),
            (LDS_AS void*)(base + 512), 16, 0, 0);
    };
    auto STAGE_B = [&](int tt, int h) {
        uint16_t* base = &smem[32768 + (tt & 1) * 16384 + h * 8192 + ldsW];
        __builtin_amdgcn_global_load_lds(
            (GLOBAL_AS void*)(bb + (size_t)(t0 + h * 128 + r0) * DD + tt * 64 + l0),
            (LDS_AS void*)(base), 16, 0, 0);
        __builtin_amdgcn_global_load_lds(
            (GLOBAL_AS void*)(bb + (size_t)(t0 + h * 128 + r1) * DD + tt * 64 + l1),
            (LDS_AS void*)(base + 512), 16, 0, 0);
    };

    STAGE_A(0, 0); STAGE_A(0, 1); STAGE_B(0, 0); STAGE_B(0, 1);
    STAGE_B(1, 0); STAGE_B(1, 1);
    asm volatile("s_waitcnt vmcnt(4)" ::: "memory");
    __builtin_amdgcn_s_barrier();

    half8 aF[4], aF2[4], bF[4][2];

    for (int t = 0; t < NTB; ++t) {
        const int abase = (t & 1) * 16384;
        const int bbase = (t & 1) * 16384;

#pragma unroll
        for (int nt = 0; nt < 4; ++nt) {
            bF[nt][0] = *(const half8*)&smem[bbase + boff + nt * 1024 + sl0];
            bF[nt][1] = *(const half8*)&smem[bbase + boff + nt * 1024 + (sl0 ^ 32)];
        }
#pragma unroll
        for (int m = 0; m < 4; ++m)
            aF[m] = *(const half8*)&smem[abase + aoff + m * 1024 + sl0];
        if (t + 1 < NTB) STAGE_A(t + 1, 0);
        __builtin_amdgcn_s_barrier();
        asm volatile("s_waitcnt lgkmcnt(0)" ::: "memory");
        __builtin_amdgcn_s_setprio(1);
#pragma unroll
        for (int m = 0; m < 4; ++m)
#pragma unroll
            for (int nt = 0; nt < 4; ++nt)
                acc[m][nt] = __builtin_amdgcn_mfma_f32_16x16x32_f16(aF[m], bF[nt][0], acc[m][nt], 0, 0, 0);
        __builtin_amdgcn_s_setprio(0);
        __builtin_amdgcn_s_barrier();

#pragma unroll
        for (int m = 0; m < 4; ++m)
            aF2[m] = *(const half8*)&smem[abase + aoff + (m + 4) * 1024 + sl0];
        if (t + 1 < NTB) STAGE_A(t + 1, 1);
        __builtin_amdgcn_s_barrier();
        asm volatile("s_waitcnt lgkmcnt(0)" ::: "memory");
        __builtin_amdgcn_s_setprio(1);
#pragma unroll
        for (int m = 0; m < 4; ++m)
#pragma unroll
            for (int nt = 0; nt < 4; ++nt)
                acc[m + 4][nt] = __builtin_amdgcn_mfma_f32_16x16x32_f16(aF2[m], bF[nt][0], acc[m + 4][nt], 0, 0, 0);
        __builtin_amdgcn_s_setprio(0);
        __builtin_amdgcn_s_barrier();

#pragma unroll
        for (int m = 0; m < 4; ++m)
            aF[m] = *(const half8*)&smem[abase + aoff + m * 1024 + (sl0 ^ 32)];
        if (t + 2 < NTB) STAGE_B(t + 2, 0);
        __builtin_amdgcn_s_barrier();
        asm volatile("s_waitcnt lgkmcnt(0)" ::: "memory");
        __builtin_amdgcn_s_setprio(1);
#pragma unroll
        for (int m = 0; m < 4; ++m)
#pragma unroll
            for (int nt = 0; nt < 4; ++nt)
                acc[m][nt] = __builtin_amdgcn_mfma_f32_16x16x32_f16(aF[m], bF[nt][1], acc[m][nt], 0, 0, 0);
        __builtin_amdgcn_s_setprio(0);
        __builtin_amdgcn_s_barrier();

#pragma unroll
        for (int m = 0; m < 4; ++m)
            aF2[m] = *(const half8*)&smem[abase + aoff + (m + 4) * 1024 + (sl0 ^ 32)];
        if (t + 2 < NTB) {
            STAGE_B(t + 2, 1);
            asm volatile("s_waitcnt vmcnt(4)" ::: "memory");
        } else {
            asm volatile("s_waitcnt vmcnt(0)" ::: "memory");
        }
        __builtin_amdgcn_s_barrier();
        asm volatile("s_waitcnt lgkmcnt(0)" ::: "memory");
        __builtin_amdgcn_s_setprio(1);
#pragma unroll
        for (int m = 0; m < 4; ++m)
#pragma unroll
            for (int nt = 0; nt < 4; ++nt)
                acc[m + 4][nt] = __builtin_amdgcn_mfma_f32_16x16x32_f16(aF2[m], bF[nt][1], acc[m + 4][nt], 0, 0, 0);
        __builtin_amdgcn_s_setprio(0);
        __builtin_amdgcn_s_barrier();
    }

    float* ob = out + (size_t)b * SS * SS;
#pragma unroll
    for (int mt = 0; mt < 8; ++mt) {
#pragma unroll
        for (int nt = 0; nt < 4; ++nt) {
            const int srow = s0 + wm * 128 + mt * 16 + quad * 4;
            const int tcol = t0 + wn * 64 + nt * 16 + fm;
#pragma unroll
            for (int reg = 0; reg < 4; ++reg)
                ob[(size_t)(srow + reg) * SS + tcol] = acc[mt][nt][reg];
        }
    }
}

extern "C" void kernel_launch(void* const* d_in, const int* in_sizes, int n_in,
                              void* d_out, int out_size, void* d_ws, size_t ws_size,
                              hipStream_t stream) {
    const float* q = (const float*)d_in[0];
    const float* k = (const float*)d_in[1];
    float* out = (float*)d_out;

    uint16_t* qk  = (uint16_t*)d_ws;                   // 4*2048*2048
    uint16_t* qT  = qk + (size_t)BATCH * SS * SS;      // 4*512*2048
    uint16_t* qH  = qT + (size_t)BATCH * DD * SS;      // 4*2048*512
    uint16_t* kH  = qH + (size_t)BATCH * SS * DD;      // 4*2048*512
    uint16_t* tmp = kH + (size_t)BATCH * SS * DD;      // 4*2048*512

    prep_kernel<<<dim3(32, 9, BATCH), 256, 0, stream>>>(q, k, qT, qH, kH);
    gemm1_kernel<<<dim3(SS / 256, SS / 256, BATCH), 512, 0, stream>>>(qH, kH, qk);
    softmax_inplace<<<dim3(BATCH * SS), 256, 0, stream>>>(qk);
    gemm2a_kernel<<<dim3(DD / 128, SS / 128, BATCH), 512, 0, stream>>>(qk, qT, tmp);
    gemm2b_kernel<<<dim3(SS / 256, SS / 256, BATCH), 512, 0, stream>>>(tmp, kH, out);
}